// Round 10
// baseline (255.754 us; speedup 1.0000x reference)
//
#include <hip/hip_runtime.h>
#include <stdint.h>

using bf16x8 = __attribute__((ext_vector_type(8))) __bf16;
using f32x4  = __attribute__((ext_vector_type(4))) float;
using us4    = __attribute__((ext_vector_type(4))) unsigned short;
using f4     = __attribute__((ext_vector_type(4))) float;

__device__ __forceinline__ unsigned short f2bf(float f) {
  unsigned u = __builtin_bit_cast(unsigned, f);
  return (unsigned short)((u + 0x7fffu + ((u >> 16) & 1u)) >> 16);  // RTNE
}

__device__ __forceinline__ unsigned cvt_pk_bf16(float lo, float hi) {
  unsigned r;
  asm("v_cvt_pk_bf16_f32 %0, %1, %2" : "=v"(r) : "v"(lo), "v"(hi));
  return r;
}

__device__ __forceinline__ void gload_lds16(const unsigned short* g, unsigned short* l) {
  __builtin_amdgcn_global_load_lds(
      (const __attribute__((address_space(1))) unsigned int*)g,
      (__attribute__((address_space(3))) unsigned int*)l, 16, 0, 0);
}

// scores in log2 domain: fold (1/sqrt(64)) * log2(e) into Q
#define QSCALE 0.18033688011112043f

// ---------------- fp32 -> bf16 elementwise ----------------
__global__ __launch_bounds__(256) void cvt_bf16_kernel(const float* __restrict__ x,
                                                       unsigned short* __restrict__ y, int n) {
  int i = (blockIdx.x * 256 + threadIdx.x) * 4;
  if (i >= n) return;
  f4 v = *(const f4*)(x + i);
  us4 o;
#pragma unroll
  for (int j = 0; j < 4; ++j) o[j] = f2bf(v[j]);
  *(us4*)(y + i) = o;
}

// ---------------- W [K][N] fp32 -> Wt [N][K] bf16 ----------------
__global__ __launch_bounds__(256) void transpose_cvt_kernel(const float* __restrict__ W,
                                                            unsigned short* __restrict__ Wt,
                                                            int K, int N) {
  __shared__ float tile[32][33];
  int n0 = blockIdx.x * 32, k0 = blockIdx.y * 32;
  int tx = threadIdx.x & 31, ty = threadIdx.x >> 5;
#pragma unroll
  for (int i = 0; i < 4; ++i)
    tile[ty + i * 8][tx] = W[(size_t)(k0 + ty + i * 8) * N + n0 + tx];
  __syncthreads();
#pragma unroll
  for (int i = 0; i < 4; ++i)
    Wt[(size_t)(n0 + ty + i * 8) * K + k0 + tx] = f2bf(tile[tx][ty + i * 8]);
}

// ---------------- QKV GEMM: 128x192 tile, 6 waves, triple-buffered ----------------
// C[M][3072] = A[M][K]*Bt[3072][K]^T + bias, scattered to Q/K/V.
// Tile 128(M) x 192(N) = exactly one head's QKV block column (head = bn).
// 6 waves as 2M x 3N of 64x64; wave wc: 0=Q, 1=K, 2=V (region-pure, 192=3*64).
// Q/K waves use SWAPPED mfma(bf,af): D lane=C-row, regs=4 consecutive C-cols
//   -> us4 (8B) coalesced-ish stores into row-major Q/K.
// V wave uses normal mfma(af,bf): regs=4 consecutive rows(seq) -> us4 into V^T.
// Triple-buffer LDS (3 x 20 KB = 60 KB -> 2 independent blocks/CU, 12 waves):
// stage tile T+2 during T -> 2 full tiles of flight; tile-end wait keeps
// exactly T+2's own loads outstanding (waves 0-1: 4 loads, waves 2-5: 3).
// Grid 64x16 = 1024 blocks @ 2/CU = exactly 2.0 rounds.
__global__ __launch_bounds__(384, 4) void gemmQKV_kernel(
    const unsigned short* __restrict__ A, const unsigned short* __restrict__ Bt,
    const float* __restrict__ bias, unsigned short* __restrict__ outQ,
    unsigned short* __restrict__ outK, unsigned short* __restrict__ outV, int K) {
  __shared__ unsigned short As[3][128 * 32];  // 8 KB / buf
  __shared__ unsigned short Bs[3][192 * 32];  // 12 KB / buf
  const int tid = threadIdx.x;
  const int lane = tid & 63, wave = tid >> 6;
  const int l16 = lane & 15, lhi = lane >> 4;
  const int wr = wave / 3, wc = wave % 3;  // 2M x 3N

  const int nwg = gridDim.x, cpx = nwg >> 3;  // bijective XCD swizzle (grid%8==0)
  const int id = (blockIdx.x & 7) * cpx + (blockIdx.x >> 3);
  const int bm = id >> 4, bn = id & 15;  // 64 x 16; head = bn

  const unsigned short* Ab = A + (size_t)bm * 128 * K;
  const unsigned short* Bb = Bt + (size_t)bn * 192 * K;
  const int NT = K >> 5;

  // staging: 1280 16B-chunks (A 512 + B 768) over 384 threads; waves 0-1 do 4,
  // waves 2-5 do 3 (boundary at tid=128 = wave edge -> no divergence).
  // Linear LDS dest + pre-swizzled global col (rule #21): cs = c ^ ((r>>1)&3).
  auto stage = [&](int buf, int T) {
#pragma unroll
    for (int i = 0; i < 4; ++i) {
      int ci = i * 384 + tid;
      if (i == 3 && ci >= 1280) break;
      if (ci < 512) {
        int r = ci >> 2, c = ci & 3, cs = c ^ ((r >> 1) & 3);
        gload_lds16(Ab + (size_t)r * K + T * 32 + cs * 8, &As[buf][ci * 8]);
      } else {
        int cj = ci - 512;
        int r = cj >> 2, c = cj & 3, cs = c ^ ((r >> 1) & 3);
        gload_lds16(Bb + (size_t)r * K + T * 32 + cs * 8, &Bs[buf][cj * 8]);
      }
    }
  };
  // ds_read chunk index: lhi ^ ((l16>>1)&3) -> 2-way bank alias (free)
  const int crd = (lhi ^ ((l16 >> 1) & 3)) * 8;

  f32x4 acc[4][4] = {};

  stage(0, 0);
  stage(1, 1);
  if (wave < 2) asm volatile("s_waitcnt vmcnt(4)" ::: "memory");
  else          asm volatile("s_waitcnt vmcnt(3)" ::: "memory");
  __builtin_amdgcn_s_barrier();

  int bR = 0;
#pragma unroll 1
  for (int T = 0; T < NT; ++T) {
    int bS = bR + 2;
    if (bS >= 3) bS -= 3;
    const bool st = (T + 2 < NT);
    if (st) stage(bS, T + 2);

    const unsigned short* Ac = &As[bR][0];
    const unsigned short* Bc = &Bs[bR][0];
    bf16x8 af[4], bf[4];
#pragma unroll
    for (int m = 0; m < 4; ++m)
      af[m] = *(const bf16x8*)(Ac + (wr * 64 + m * 16 + l16) * 32 + crd);
#pragma unroll
    for (int n = 0; n < 4; ++n)
      bf[n] = *(const bf16x8*)(Bc + (wc * 64 + n * 16 + l16) * 32 + crd);

    __builtin_amdgcn_s_setprio(1);
    if (wc < 2) {  // Q/K: swapped operands -> lane = C-row
#pragma unroll
      for (int m = 0; m < 4; ++m)
#pragma unroll
        for (int n = 0; n < 4; ++n)
          acc[m][n] = __builtin_amdgcn_mfma_f32_16x16x32_bf16(bf[n], af[m], acc[m][n], 0, 0, 0);
    } else {  // V: normal -> regs = 4 consecutive seq rows for V^T
#pragma unroll
      for (int m = 0; m < 4; ++m)
#pragma unroll
        for (int n = 0; n < 4; ++n)
          acc[m][n] = __builtin_amdgcn_mfma_f32_16x16x32_bf16(af[m], bf[n], acc[m][n], 0, 0, 0);
    }
    __builtin_amdgcn_s_setprio(0);

    if (st) {
      if (wave < 2) asm volatile("s_waitcnt vmcnt(4)" ::: "memory");
      else          asm volatile("s_waitcnt vmcnt(3)" ::: "memory");
    } else if (T + 1 < NT) {
      asm volatile("s_waitcnt vmcnt(0)" ::: "memory");
    }
    __builtin_amdgcn_s_barrier();
    bR = bR + 1;
    if (bR == 3) bR = 0;
  }

  // epilogue: head = bn; wave wc: 0=Q 1=K 2=V.
  if (wc < 2) {
    // swapped frags: row = ...+mf*16+l16 ; cols = nf*16+lhi*4 + rr (consecutive)
    unsigned short* dst = (wc == 0) ? outQ : outK;
#pragma unroll
    for (int mf = 0; mf < 4; ++mf) {
      int gr = bm * 128 + wr * 64 + mf * 16 + l16;
      int b = gr >> 11, l = gr & 2047;
      size_t base = ((size_t)(b * 16 + bn) * 2048 + l) * 64;
#pragma unroll
      for (int nf = 0; nf < 4; ++nf) {
        int j0 = nf * 16 + lhi * 4;
        f4 bi = *(const f4*)&bias[bn * 192 + wc * 64 + j0];
        us4 o;
#pragma unroll
        for (int rr = 0; rr < 4; ++rr) {
          float v = acc[mf][nf][rr] + bi[rr];
          o[rr] = f2bf(wc == 0 ? v * QSCALE : v);
        }
        *(us4*)&dst[base + j0] = o;
      }
    }
  } else {
    // normal frags: col d = nf*16+l16 ; rows l0 = ...+mf*16+lhi*4 + rr
#pragma unroll
    for (int nf = 0; nf < 4; ++nf) {
      int d = nf * 16 + l16;
      float bi = bias[bn * 192 + 128 + d];
#pragma unroll
      for (int mf = 0; mf < 4; ++mf) {
        int l0 = bm * 128 + wr * 64 + mf * 16 + lhi * 4;
        int b = l0 >> 11, l = l0 & 2047;
        us4 o;
#pragma unroll
        for (int rr = 0; rr < 4; ++rr) o[rr] = f2bf(acc[mf][nf][rr] + bi);
        *(us4*)&outV[((size_t)(b * 16 + bn) * 64 + d) * 2048 + l] = o;
      }
    }
  }
}

// ---------------- out-proj GEMM: 128x128, 4 waves, triple-buffered, swapped C ----------------
__global__ __launch_bounds__(256, 4) void gemmO_kernel(
    const unsigned short* __restrict__ A, const unsigned short* __restrict__ Bt,
    const float* __restrict__ bias, float* __restrict__ outF, int N, int K) {
  __shared__ unsigned short As[3][128 * 32];
  __shared__ unsigned short Bs[3][128 * 32];
  const int tid = threadIdx.x;
  const int lane = tid & 63, wave = tid >> 6;
  const int l16 = lane & 15, lhi = lane >> 4;
  const int wr = wave >> 1, wc = wave & 1;

  const int nwg = gridDim.x, cpx = nwg >> 3;
  const int id = (blockIdx.x & 7) * cpx + (blockIdx.x >> 3);
  const int bm = id >> 3, bn = id & 7;  // 64 x 8

  const unsigned short* Ab = A + (size_t)bm * 128 * K;
  const unsigned short* Bb = Bt + (size_t)bn * 128 * K;
  const int NT = K >> 5;

  auto stage = [&](int buf, int T) {  // 1024 chunks / 256 thr = 4 each (uniform)
#pragma unroll
    for (int i = 0; i < 2; ++i) {
      int ci = i * 256 + tid;
      int r = ci >> 2, c = ci & 3, cs = c ^ ((r >> 1) & 3);
      gload_lds16(Ab + (size_t)r * K + T * 32 + cs * 8, &As[buf][ci * 8]);
      gload_lds16(Bb + (size_t)r * K + T * 32 + cs * 8, &Bs[buf][ci * 8]);
    }
  };
  const int crd = (lhi ^ ((l16 >> 1) & 3)) * 8;

  f32x4 acc[4][4] = {};

  stage(0, 0);
  stage(1, 1);
  asm volatile("s_waitcnt vmcnt(4)" ::: "memory");
  __builtin_amdgcn_s_barrier();

  int bR = 0;
#pragma unroll 1
  for (int T = 0; T < NT; ++T) {
    int bS = bR + 2;
    if (bS >= 3) bS -= 3;
    const bool st = (T + 2 < NT);
    if (st) stage(bS, T + 2);

    const unsigned short* Ac = &As[bR][0];
    const unsigned short* Bc = &Bs[bR][0];
    bf16x8 af[4], bf[4];
#pragma unroll
    for (int m = 0; m < 4; ++m)
      af[m] = *(const bf16x8*)(Ac + (wr * 64 + m * 16 + l16) * 32 + crd);
#pragma unroll
    for (int n = 0; n < 4; ++n)
      bf[n] = *(const bf16x8*)(Bc + (wc * 64 + n * 16 + l16) * 32 + crd);

    __builtin_amdgcn_s_setprio(1);
#pragma unroll
    for (int m = 0; m < 4; ++m)
#pragma unroll
      for (int n = 0; n < 4; ++n)
        acc[m][n] = __builtin_amdgcn_mfma_f32_16x16x32_bf16(bf[n], af[m], acc[m][n], 0, 0, 0);
    __builtin_amdgcn_s_setprio(0);

    if (st)
      asm volatile("s_waitcnt vmcnt(4)" ::: "memory");
    else if (T + 1 < NT)
      asm volatile("s_waitcnt vmcnt(0)" ::: "memory");
    __builtin_amdgcn_s_barrier();
    bR = bR + 1;
    if (bR == 3) bR = 0;
  }

  // swapped C: lane = row, regs = 4 consecutive cols -> float4 stores
#pragma unroll
  for (int mf = 0; mf < 4; ++mf) {
    int gr = bm * 128 + wr * 64 + mf * 16 + l16;
#pragma unroll
    for (int nf = 0; nf < 4; ++nf) {
      int gc0 = bn * 128 + wc * 64 + nf * 16 + lhi * 4;
      f4 bi = *(const f4*)&bias[gc0];
      f4 o;
#pragma unroll
      for (int rr = 0; rr < 4; ++rr) o[rr] = acc[mf][nf][rr] + bi[rr];
      *(f4*)&outF[(size_t)gr * N + gc0] = o;
    }
  }
}

// ---------------- causal flash attention v3 (unchanged) ----------------
__global__ __launch_bounds__(256) void attn_kernel(const unsigned short* __restrict__ Q,
                                                   const unsigned short* __restrict__ K,
                                                   const unsigned short* __restrict__ Vt,
                                                   unsigned short* __restrict__ Ao) {
  __shared__ unsigned short Ks[2][4096];
  __shared__ unsigned short Vs[2][4096];
  __shared__ unsigned short Plds[4][1024];

  const int qtA = blockIdx.x, bh = blockIdx.y;
  const int tid = threadIdx.x;
  const int lane = tid & 63, wave = tid >> 6;
  const int l16 = lane & 15, lhi = lane >> 4;

  const unsigned short* Qp = Q + (size_t)bh * 2048 * 64;
  const unsigned short* Kp = K + (size_t)bh * 2048 * 64;
  const unsigned short* Vp = Vt + (size_t)bh * 64 * 2048;
  const int b = bh >> 4, h = bh & 15;

  const int swz = (l16 & 7) << 3;
  const int kc0 = (lhi * 16) ^ ((l16 & 7) << 4);

  auto stage = [&](int buf, int k0) {
#pragma unroll
    for (int i = 0; i < 2; ++i) {
      int c = tid + 256 * i;
      int row = c >> 3;
      int col16 = (c & 7) ^ (row & 7);
      gload_lds16(Kp + (size_t)(k0 + row) * 64 + col16 * 8, &Ks[buf][c * 8]);
      gload_lds16(Vp + (size_t)row * 2048 + k0 + col16 * 8, &Vs[buf][c * 8]);
    }
  };

#pragma unroll 1
  for (int phase = 0; phase < 2; ++phase) {
    const int qt = phase ? (31 - qtA) : qtA;
    const int qbase = qt * 64 + wave * 16;
    const int qrow = qbase + l16;
    const int ntile = qt + 1;

    stage(0, 0);
    bf16x8 qf0 = *(const bf16x8*)&Qp[(size_t)(qbase + l16) * 64 + lhi * 8];
    bf16x8 qf1 = *(const bf16x8*)&Qp[(size_t)(qbase + l16) * 64 + 32 + lhi * 8];

    f32x4 o[4] = {};
    float mi = -1e30f, li = 0.f;

    asm volatile("s_waitcnt vmcnt(0)" ::: "memory");
    __syncthreads();

    int cur = 0;
#pragma unroll 1
    for (int kt = 0; kt < ntile; ++kt) {
      const int k0 = kt * 64;
      if (kt + 1 < ntile) stage(cur ^ 1, k0 + 64);

      const char* kb = (const char*)Ks[cur];
      f32x4 st[4];
      __builtin_amdgcn_s_setprio(1);
#pragma unroll
      for (int j = 0; j < 4; ++j) {
        const char* kr = kb + (16 * j + l16) * 128;
        bf16x8 kf0 = *(const bf16x8*)(kr + kc0);
        bf16x8 kf1 = *(const bf16x8*)(kr + (kc0 ^ 64));
        f32x4 z = {};
        z = __builtin_amdgcn_mfma_f32_16x16x32_bf16(kf0, qf0, z, 0, 0, 0);
        st[j] = __builtin_amdgcn_mfma_f32_16x16x32_bf16(kf1, qf1, z, 0, 0, 0);
      }
      __builtin_amdgcn_s_setprio(0);

      float p[16];
      float mv = -1e30f;
      if (k0 + 63 <= qbase) {
#pragma unroll
        for (int j = 0; j < 4; ++j)
#pragma unroll
          for (int r = 0; r < 4; ++r) {
            float v = st[j][r];
            p[j * 4 + r] = v;
            mv = fmaxf(mv, v);
          }
      } else {
#pragma unroll
        for (int j = 0; j < 4; ++j)
#pragma unroll
          for (int r = 0; r < 4; ++r) {
            int key = k0 + 16 * j + 4 * lhi + r;
            float v = (key <= qrow) ? st[j][r] : -1e30f;
            p[j * 4 + r] = v;
            mv = fmaxf(mv, v);
          }
      }
      mv = fmaxf(mv, __shfl_xor(mv, 16));
      mv = fmaxf(mv, __shfl_xor(mv, 32));
      if (!__all(mv <= mi + 8.0f)) {
        float mnew = fmaxf(mi, mv);
        float alpha = __builtin_amdgcn_exp2f(mi - mnew);
#pragma unroll
        for (int c = 0; c < 4; ++c)
#pragma unroll
          for (int r = 0; r < 4; ++r) o[c][r] *= alpha;
        li *= alpha;
        mi = mnew;
      }
      float sum = 0.f;
#pragma unroll
      for (int i = 0; i < 16; ++i) {
        p[i] = __builtin_amdgcn_exp2f(p[i] - mi);
        sum += p[i];
      }
      sum += __shfl_xor(sum, 16);
      sum += __shfl_xor(sum, 32);
      li += sum;

#pragma unroll
      for (int j = 0; j < 4; ++j) {
        uint2 w;
        w.x = cvt_pk_bf16(p[j * 4 + 0], p[j * 4 + 1]);
        w.y = cvt_pk_bf16(p[j * 4 + 2], p[j * 4 + 3]);
        *(uint2*)&Plds[wave][l16 * 64 + ((j * 16 + 4 * lhi) ^ swz)] = w;
      }
      asm volatile("s_waitcnt lgkmcnt(0)" ::: "memory");
      __builtin_amdgcn_sched_barrier(0);

      const char* vb = (const char*)Vs[cur];
      __builtin_amdgcn_s_setprio(1);
#pragma unroll
      for (int c2 = 0; c2 < 2; ++c2) {
        bf16x8 pf = *(const bf16x8*)&Plds[wave][l16 * 64 + ((c2 * 32 + lhi * 8) ^ swz)];
#pragma unroll
        for (int c = 0; c < 4; ++c) {
          bf16x8 vf = *(const bf16x8*)(vb + (c * 16 + l16) * 128 + (kc0 ^ (c2 * 64)));
          o[c] = __builtin_amdgcn_mfma_f32_16x16x32_bf16(vf, pf, o[c], 0, 0, 0);
        }
      }
      __builtin_amdgcn_s_setprio(0);

      asm volatile("s_waitcnt vmcnt(0)" ::: "memory");
      __syncthreads();
      cur ^= 1;
    }

    float invl = 1.0f / li;
    size_t rowb = (size_t)(b * 2048 + qbase + l16) * 1024 + h * 64;
#pragma unroll
    for (int c = 0; c < 4; ++c) {
      uint2 w;
      w.x = cvt_pk_bf16(o[c][0] * invl, o[c][1] * invl);
      w.y = cvt_pk_bf16(o[c][2] * invl, o[c][3] * invl);
      *(uint2*)&Ao[rowb + c * 16 + lhi * 4] = w;
    }
  }
}

extern "C" void kernel_launch(void* const* d_in, const int* in_sizes, int n_in,
                              void* d_out, int out_size, void* d_ws, size_t ws_size,
                              hipStream_t stream) {
  const float* X    = (const float*)d_in[0];
  const float* Wqkv = (const float*)d_in[1];
  const float* bqkv = (const float*)d_in[2];
  const float* Wout = (const float*)d_in[3];
  const float* bout = (const float*)d_in[4];
  float* out = (float*)d_out;

  unsigned short* ws     = (unsigned short*)d_ws;
  unsigned short* Xb     = ws;                   // 8192*1024
  unsigned short* Wqkv_t = Xb + 8388608;         // 3072*1024
  unsigned short* Wout_t = Wqkv_t + 3145728;     // 1024*1024
  unsigned short* Qb     = Wout_t + 1048576;     // [B,H,S,64]
  unsigned short* Kb     = Qb + 8388608;         // [B,H,S,64]
  unsigned short* Vtb    = Kb + 8388608;         // [B,H,64,S]
  unsigned short* Aob    = Vtb + 8388608;        // [B*S,1024]

  cvt_bf16_kernel<<<8192, 256, 0, stream>>>(X, Xb, 8388608);
  transpose_cvt_kernel<<<dim3(3072 / 32, 1024 / 32), 256, 0, stream>>>(Wqkv, Wqkv_t, 1024, 3072);
  transpose_cvt_kernel<<<dim3(1024 / 32, 1024 / 32), 256, 0, stream>>>(Wout, Wout_t, 1024, 1024);
  gemmQKV_kernel<<<1024, 384, 0, stream>>>(Xb, Wqkv_t, bqkv, Qb, Kb, Vtb, 1024);
  attn_kernel<<<dim3(16, 64), 256, 0, stream>>>(Qb, Kb, Vtb, Aob);
  gemmO_kernel<<<512, 256, 0, stream>>>(Aob, Wout_t, bout, out, 1024, 1024);
}

// Round 11
// 206.128 us; speedup vs baseline: 1.2408x; 1.2408x over previous
//
#include <hip/hip_runtime.h>
#include <stdint.h>

using bf16x8 = __attribute__((ext_vector_type(8))) __bf16;
using f32x4  = __attribute__((ext_vector_type(4))) float;
using f32x16 = __attribute__((ext_vector_type(16))) float;
using us4    = __attribute__((ext_vector_type(4))) unsigned short;
using f4     = __attribute__((ext_vector_type(4))) float;

__device__ __forceinline__ unsigned short f2bf(float f) {
  unsigned u = __builtin_bit_cast(unsigned, f);
  return (unsigned short)((u + 0x7fffu + ((u >> 16) & 1u)) >> 16);  // RTNE
}

__device__ __forceinline__ unsigned cvt_pk_bf16(float lo, float hi) {
  unsigned r;
  asm("v_cvt_pk_bf16_f32 %0, %1, %2" : "=v"(r) : "v"(lo), "v"(hi));
  return r;
}

__device__ __forceinline__ void gload_lds16(const unsigned short* g, unsigned short* l) {
  __builtin_amdgcn_global_load_lds(
      (const __attribute__((address_space(1))) unsigned int*)g,
      (__attribute__((address_space(3))) unsigned int*)l, 16, 0, 0);
}

// scores in log2 domain: fold (1/sqrt(64)) * log2(e) into Q
#define QSCALE 0.18033688011112043f

// ---------------- fp32 -> bf16 elementwise ----------------
__global__ __launch_bounds__(256) void cvt_bf16_kernel(const float* __restrict__ x,
                                                       unsigned short* __restrict__ y, int n) {
  int i = (blockIdx.x * 256 + threadIdx.x) * 4;
  if (i >= n) return;
  f4 v = *(const f4*)(x + i);
  us4 o;
#pragma unroll
  for (int j = 0; j < 4; ++j) o[j] = f2bf(v[j]);
  *(us4*)(y + i) = o;
}

// ---------------- W [K][N] fp32 -> Wt [N][K] bf16 ----------------
__global__ __launch_bounds__(256) void transpose_cvt_kernel(const float* __restrict__ W,
                                                            unsigned short* __restrict__ Wt,
                                                            int K, int N) {
  __shared__ float tile[32][33];
  int n0 = blockIdx.x * 32, k0 = blockIdx.y * 32;
  int tx = threadIdx.x & 31, ty = threadIdx.x >> 5;
#pragma unroll
  for (int i = 0; i < 4; ++i)
    tile[ty + i * 8][tx] = W[(size_t)(k0 + ty + i * 8) * N + n0 + tx];
  __syncthreads();
#pragma unroll
  for (int i = 0; i < 4; ++i)
    Wt[(size_t)(n0 + ty + i * 8) * K + k0 + tx] = f2bf(tile[tx][ty + i * 8]);
}

// ---------------- 32x32-MFMA dbuf bf16 GEMM ----------------
// C[M][N] = A[M][K]*Bt[N][K]^T + bias. Tile 256(M)x128(N), BK=32, 4 waves
// (2Mx2N), per-wave 128x64 = 4x2 frags of 32x32 (acc 8 x f32x16 = 128 VGPR).
// v_mfma_f32_32x32x16_bf16: 2x FLOP/instr and 2x FLOP/fragment-byte vs
// 16x16x32 -> per wave-tile only 12 ds_read_b128 + 16 MFMA (reads/FLOP -46%).
// LDS dbuf 48 KB -> ~2 blocks/CU; loose R3-style sync (stage T+1 during T,
// one vmcnt(0)+s_barrier per tile; cross-block overlap covers the drain).
// Chunk-XOR swizzle c^((r>>1)&3) both-sides (rule #21): 32-lane b128 read
// covers all 32 banks at the 4-pass data floor.
// A-frag map: row=lane&31, k=(lane>>5)*8+e (A,B share map -> k-perm cancels).
// C/D map (HW-verified m74/m101): col=lane&31, row=(reg&3)+8(reg>>2)+4(lane>>5).
// MODE 0: fp32 out.  MODE 1: QKV scatter (Q scaled, V transposed); each 32-col
// fragment is head- and region-pure (192-boundaries are 32-aligned).
template <int MODE, int GN>
__global__ __launch_bounds__(256, 2) void gemmW_kernel(
    const unsigned short* __restrict__ A, const unsigned short* __restrict__ Bt,
    const float* __restrict__ bias, float* __restrict__ outF,
    unsigned short* __restrict__ outQ, unsigned short* __restrict__ outK,
    unsigned short* __restrict__ outV, int N, int K) {
  __shared__ unsigned short As[2][256 * 32];  // 16 KB / buf
  __shared__ unsigned short Bs[2][128 * 32];  // 8 KB / buf   (48 KB total)
  const int tid = threadIdx.x;
  const int lane = tid & 63, wave = tid >> 6;
  const int l31 = lane & 31, lhi = lane >> 5;
  const int wr = wave >> 1, wc = wave & 1;  // 2M x 2N

  const int nwg = gridDim.x, cpx = nwg >> 3;  // bijective XCD swizzle (grid%8==0)
  const int id = (blockIdx.x & 7) * cpx + (blockIdx.x >> 3);
  const int bm = id / GN, bn = id % GN;

  const unsigned short* Ab = A + (size_t)bm * 256 * K;
  const unsigned short* Bb = Bt + (size_t)bn * 128 * K;
  const int NT = K >> 5;

  // staging: A 1024 + B 512 16B-chunks over 256 threads (6 each).
  // Linear LDS dest + pre-swizzled global col (rule #21): cs = c ^ ((r>>1)&3).
  auto stage = [&](int buf, int T) {
#pragma unroll
    for (int i = 0; i < 6; ++i) {
      int ci = i * 256 + tid;
      if (ci < 1024) {
        int r = ci >> 2, c = ci & 3, cs = c ^ ((r >> 1) & 3);
        gload_lds16(Ab + (size_t)r * K + T * 32 + cs * 8, &As[buf][ci * 8]);
      } else {
        int cj = ci - 1024;
        int r = cj >> 2, c = cj & 3, cs = c ^ ((r >> 1) & 3);
        gload_lds16(Bb + (size_t)r * K + T * 32 + cs * 8, &Bs[buf][cj * 8]);
      }
    }
  };
  // ds_read chunk (16B units) for k-slice ks: (ks*2 + lhi) ^ ((l31>>1)&3)
  const int sw = (l31 >> 1) & 3;
  const int ck0 = (0 * 2 + lhi) ^ sw;
  const int ck1 = (1 * 2 + lhi) ^ sw;

  f32x16 acc[4][2] = {};

  stage(0, 0);
  asm volatile("s_waitcnt vmcnt(0)" ::: "memory");
  __builtin_amdgcn_s_barrier();

#pragma unroll 1
  for (int T = 0; T < NT; ++T) {
    const int cur = T & 1;
    const unsigned short* Ac = &As[cur][0];
    const unsigned short* Bc = &Bs[cur][0];
    bf16x8 af[4][2], bf[2][2];
#pragma unroll
    for (int mm = 0; mm < 4; ++mm) {
      const unsigned short* ar = Ac + (wr * 128 + mm * 32 + l31) * 32;
      af[mm][0] = *(const bf16x8*)(ar + ck0 * 8);
      af[mm][1] = *(const bf16x8*)(ar + ck1 * 8);
    }
#pragma unroll
    for (int nn = 0; nn < 2; ++nn) {
      const unsigned short* br = Bc + (wc * 64 + nn * 32 + l31) * 32;
      bf[nn][0] = *(const bf16x8*)(br + ck0 * 8);
      bf[nn][1] = *(const bf16x8*)(br + ck1 * 8);
    }
    if (T + 1 < NT) stage(cur ^ 1, T + 1);
#pragma unroll
    for (int mm = 0; mm < 4; ++mm)
#pragma unroll
      for (int nn = 0; nn < 2; ++nn) {
        acc[mm][nn] = __builtin_amdgcn_mfma_f32_32x32x16_bf16(af[mm][0], bf[nn][0],
                                                              acc[mm][nn], 0, 0, 0);
        acc[mm][nn] = __builtin_amdgcn_mfma_f32_32x32x16_bf16(af[mm][1], bf[nn][1],
                                                              acc[mm][nn], 0, 0, 0);
      }
    if (T + 1 < NT) asm volatile("s_waitcnt vmcnt(0)" ::: "memory");
    __builtin_amdgcn_s_barrier();
  }

  // epilogue: C/D map col=lane&31, row=(reg&3)+8*(reg>>2)+4*(lane>>5)
#pragma unroll
  for (int mm = 0; mm < 4; ++mm) {
#pragma unroll
    for (int nn = 0; nn < 2; ++nn) {
      const int gc0 = bn * 128 + wc * 64 + nn * 32;  // wave-uniform
      const float bi = bias[gc0 + l31];
      if (MODE == 0) {
#pragma unroll
        for (int reg = 0; reg < 16; ++reg) {
          int gr = bm * 256 + wr * 128 + mm * 32 + (reg & 3) + 8 * (reg >> 2) + 4 * lhi;
          outF[(size_t)gr * N + gc0 + l31] = acc[mm][nn][reg] + bi;
        }
      } else {
        const int head = gc0 / 192;          // uniform per fragment
        const int j0 = gc0 - head * 192;     // 0,32 =Q; 64,96 =K; 128,160 =V
        if (j0 < 128) {
          unsigned short* dst = (j0 < 64) ? outQ : outK;
          const int joff = (j0 < 64) ? j0 : (j0 - 64);
          const float sc = (j0 < 64) ? QSCALE : 1.0f;
#pragma unroll
          for (int reg = 0; reg < 16; ++reg) {
            int gr = bm * 256 + wr * 128 + mm * 32 + (reg & 3) + 8 * (reg >> 2) + 4 * lhi;
            int b = gr >> 11, l = gr & 2047;
            dst[((size_t)(b * 16 + head) * 2048 + l) * 64 + joff + l31] =
                f2bf((acc[mm][nn][reg] + bi) * sc);
          }
        } else {
          const int d = j0 - 128 + l31;
#pragma unroll
          for (int reg = 0; reg < 16; ++reg) {
            int gr = bm * 256 + wr * 128 + mm * 32 + (reg & 3) + 8 * (reg >> 2) + 4 * lhi;
            int b = gr >> 11, l = gr & 2047;
            outV[((size_t)(b * 16 + head) * 64 + d) * 2048 + l] = f2bf(acc[mm][nn][reg] + bi);
          }
        }
      }
    }
  }
}

// ---------------- causal flash attention v3 (unchanged) ----------------
__global__ __launch_bounds__(256) void attn_kernel(const unsigned short* __restrict__ Q,
                                                   const unsigned short* __restrict__ K,
                                                   const unsigned short* __restrict__ Vt,
                                                   unsigned short* __restrict__ Ao) {
  __shared__ unsigned short Ks[2][4096];
  __shared__ unsigned short Vs[2][4096];
  __shared__ unsigned short Plds[4][1024];

  const int qtA = blockIdx.x, bh = blockIdx.y;
  const int tid = threadIdx.x;
  const int lane = tid & 63, wave = tid >> 6;
  const int l16 = lane & 15, lhi = lane >> 4;

  const unsigned short* Qp = Q + (size_t)bh * 2048 * 64;
  const unsigned short* Kp = K + (size_t)bh * 2048 * 64;
  const unsigned short* Vp = Vt + (size_t)bh * 64 * 2048;
  const int b = bh >> 4, h = bh & 15;

  const int swz = (l16 & 7) << 3;
  const int kc0 = (lhi * 16) ^ ((l16 & 7) << 4);

  auto stage = [&](int buf, int k0) {
#pragma unroll
    for (int i = 0; i < 2; ++i) {
      int c = tid + 256 * i;
      int row = c >> 3;
      int col16 = (c & 7) ^ (row & 7);
      gload_lds16(Kp + (size_t)(k0 + row) * 64 + col16 * 8, &Ks[buf][c * 8]);
      gload_lds16(Vp + (size_t)row * 2048 + k0 + col16 * 8, &Vs[buf][c * 8]);
    }
  };

#pragma unroll 1
  for (int phase = 0; phase < 2; ++phase) {
    const int qt = phase ? (31 - qtA) : qtA;
    const int qbase = qt * 64 + wave * 16;
    const int qrow = qbase + l16;
    const int ntile = qt + 1;

    stage(0, 0);
    bf16x8 qf0 = *(const bf16x8*)&Qp[(size_t)(qbase + l16) * 64 + lhi * 8];
    bf16x8 qf1 = *(const bf16x8*)&Qp[(size_t)(qbase + l16) * 64 + 32 + lhi * 8];

    f32x4 o[4] = {};
    float mi = -1e30f, li = 0.f;

    asm volatile("s_waitcnt vmcnt(0)" ::: "memory");
    __syncthreads();

    int cur = 0;
#pragma unroll 1
    for (int kt = 0; kt < ntile; ++kt) {
      const int k0 = kt * 64;
      if (kt + 1 < ntile) stage(cur ^ 1, k0 + 64);

      const char* kb = (const char*)Ks[cur];
      f32x4 st[4];
      __builtin_amdgcn_s_setprio(1);
#pragma unroll
      for (int j = 0; j < 4; ++j) {
        const char* kr = kb + (16 * j + l16) * 128;
        bf16x8 kf0 = *(const bf16x8*)(kr + kc0);
        bf16x8 kf1 = *(const bf16x8*)(kr + (kc0 ^ 64));
        f32x4 z = {};
        z = __builtin_amdgcn_mfma_f32_16x16x32_bf16(kf0, qf0, z, 0, 0, 0);
        st[j] = __builtin_amdgcn_mfma_f32_16x16x32_bf16(kf1, qf1, z, 0, 0, 0);
      }
      __builtin_amdgcn_s_setprio(0);

      float p[16];
      float mv = -1e30f;
      if (k0 + 63 <= qbase) {
#pragma unroll
        for (int j = 0; j < 4; ++j)
#pragma unroll
          for (int r = 0; r < 4; ++r) {
            float v = st[j][r];
            p[j * 4 + r] = v;
            mv = fmaxf(mv, v);
          }
      } else {
#pragma unroll
        for (int j = 0; j < 4; ++j)
#pragma unroll
          for (int r = 0; r < 4; ++r) {
            int key = k0 + 16 * j + 4 * lhi + r;
            float v = (key <= qrow) ? st[j][r] : -1e30f;
            p[j * 4 + r] = v;
            mv = fmaxf(mv, v);
          }
      }
      mv = fmaxf(mv, __shfl_xor(mv, 16));
      mv = fmaxf(mv, __shfl_xor(mv, 32));
      if (!__all(mv <= mi + 8.0f)) {
        float mnew = fmaxf(mi, mv);
        float alpha = __builtin_amdgcn_exp2f(mi - mnew);
#pragma unroll
        for (int c = 0; c < 4; ++c)
#pragma unroll
          for (int r = 0; r < 4; ++r) o[c][r] *= alpha;
        li *= alpha;
        mi = mnew;
      }
      float sum = 0.f;
#pragma unroll
      for (int i = 0; i < 16; ++i) {
        p[i] = __builtin_amdgcn_exp2f(p[i] - mi);
        sum += p[i];
      }
      sum += __shfl_xor(sum, 16);
      sum += __shfl_xor(sum, 32);
      li += sum;

#pragma unroll
      for (int j = 0; j < 4; ++j) {
        uint2 w;
        w.x = cvt_pk_bf16(p[j * 4 + 0], p[j * 4 + 1]);
        w.y = cvt_pk_bf16(p[j * 4 + 2], p[j * 4 + 3]);
        *(uint2*)&Plds[wave][l16 * 64 + ((j * 16 + 4 * lhi) ^ swz)] = w;
      }
      asm volatile("s_waitcnt lgkmcnt(0)" ::: "memory");
      __builtin_amdgcn_sched_barrier(0);

      const char* vb = (const char*)Vs[cur];
      __builtin_amdgcn_s_setprio(1);
#pragma unroll
      for (int c2 = 0; c2 < 2; ++c2) {
        bf16x8 pf = *(const bf16x8*)&Plds[wave][l16 * 64 + ((c2 * 32 + lhi * 8) ^ swz)];
#pragma unroll
        for (int c = 0; c < 4; ++c) {
          bf16x8 vf = *(const bf16x8*)(vb + (c * 16 + l16) * 128 + (kc0 ^ (c2 * 64)));
          o[c] = __builtin_amdgcn_mfma_f32_16x16x32_bf16(vf, pf, o[c], 0, 0, 0);
        }
      }
      __builtin_amdgcn_s_setprio(0);

      asm volatile("s_waitcnt vmcnt(0)" ::: "memory");
      __syncthreads();
      cur ^= 1;
    }

    float invl = 1.0f / li;
    size_t rowb = (size_t)(b * 2048 + qbase + l16) * 1024 + h * 64;
#pragma unroll
    for (int c = 0; c < 4; ++c) {
      uint2 w;
      w.x = cvt_pk_bf16(o[c][0] * invl, o[c][1] * invl);
      w.y = cvt_pk_bf16(o[c][2] * invl, o[c][3] * invl);
      *(uint2*)&Ao[rowb + c * 16 + lhi * 4] = w;
    }
  }
}

extern "C" void kernel_launch(void* const* d_in, const int* in_sizes, int n_in,
                              void* d_out, int out_size, void* d_ws, size_t ws_size,
                              hipStream_t stream) {
  const float* X    = (const float*)d_in[0];
  const float* Wqkv = (const float*)d_in[1];
  const float* bqkv = (const float*)d_in[2];
  const float* Wout = (const float*)d_in[3];
  const float* bout = (const float*)d_in[4];
  float* out = (float*)d_out;

  unsigned short* ws     = (unsigned short*)d_ws;
  unsigned short* Xb     = ws;                   // 8192*1024
  unsigned short* Wqkv_t = Xb + 8388608;         // 3072*1024
  unsigned short* Wout_t = Wqkv_t + 3145728;     // 1024*1024
  unsigned short* Qb     = Wout_t + 1048576;     // [B,H,S,64]
  unsigned short* Kb     = Qb + 8388608;         // [B,H,S,64]
  unsigned short* Vtb    = Kb + 8388608;         // [B,H,64,S]
  unsigned short* Aob    = Vtb + 8388608;        // [B*S,1024]

  cvt_bf16_kernel<<<8192, 256, 0, stream>>>(X, Xb, 8388608);
  transpose_cvt_kernel<<<dim3(3072 / 32, 1024 / 32), 256, 0, stream>>>(Wqkv, Wqkv_t, 1024, 3072);
  transpose_cvt_kernel<<<dim3(1024 / 32, 1024 / 32), 256, 0, stream>>>(Wout, Wout_t, 1024, 1024);
  gemmW_kernel<1, 24><<<768, 256, 0, stream>>>(
      Xb, Wqkv_t, bqkv, nullptr, Qb, Kb, Vtb, 3072, 1024);
  attn_kernel<<<dim3(16, 64), 256, 0, stream>>>(Qb, Kb, Vtb, Aob);
  gemmW_kernel<0, 8><<<256, 256, 0, stream>>>(
      Aob, Wout_t, bout, out, nullptr, nullptr, nullptr, 1024, 1024);
}